// Round 2
// baseline (38.456 us; speedup 1.0000x reference)
//
#include <hip/hip_runtime.h>
#include <hip/hip_bf16.h>

// Decoder step, MI355X. Live math only:
//   pred = 0 exactly (log_softmax over size-1 axis)
//   h,c  = single LSTM cell step
// Single fused dispatch: blocks 0..99 = GEMM+LSTM epilogue (on-the-fly
// fp32->bf16 cvt, no pack pass), blocks 100.. = grid-stride zero of pred.

#define HH 400          // hidden
#define BB 256          // batch
#define PRED_N 8192000  // 256*32000
#define BH_N   102400   // 256*400
#define GEMM_BLOCKS 100
#define ZERO_BLOCKS 1948
#define TOTAL_BLOCKS (GEMM_BLOCKS + ZERO_BLOCKS)
#define HSQ (HH * HH)   // 160000: stride between gate weight planes

typedef __attribute__((ext_vector_type(8))) short short8;
typedef __attribute__((ext_vector_type(4))) float f32x4;

__device__ __forceinline__ float sigmoidf_(float x) {
    return 1.0f / (1.0f + __expf(-x));
}
__device__ __forceinline__ float tanh_stable(float x) {
    float ax = fabsf(x);
    float e  = __expf(-2.0f * ax);
    float r  = (1.0f - e) / (1.0f + e);
    return copysignf(r, x);
}

// Load 8 contiguous fp32 (32B-aligned: all row strides are 1600B) -> bf16x8.
__device__ __forceinline__ short8 cvt8(const float* __restrict__ s) {
    f32x4 v0 = *reinterpret_cast<const f32x4*>(s);
    f32x4 v1 = *reinterpret_cast<const f32x4*>(s + 4);
    union { short8 sv; __hip_bfloat16 h[8]; } u;
#pragma unroll
    for (int i = 0; i < 4; ++i) {
        u.h[i]     = __float2bfloat16(v0[i]);
        u.h[i + 4] = __float2bfloat16(v1[i]);
    }
    return u.sv;
}

__launch_bounds__(256, 2)
__global__ void decoder_fused_kernel(const int* __restrict__ prev,
                                     const float* __restrict__ h0,
                                     const float* __restrict__ c0,
                                     const float* __restrict__ emb,
                                     const float* __restrict__ wih,
                                     const float* __restrict__ whh,
                                     const float* __restrict__ bih,
                                     const float* __restrict__ bhh,
                                     float* __restrict__ out) {
    if (blockIdx.x >= GEMM_BLOCKS) {
        // ---- zero the pred region (exactly 0: log_softmax over size-1 axis) ----
        const int tid = (blockIdx.x - GEMM_BLOCKS) * 256 + threadIdx.x;
        f32x4 z = {0.f, 0.f, 0.f, 0.f};
        f32x4* p = reinterpret_cast<f32x4*>(out);
        const int nvec = PRED_N / 4;
#pragma unroll 2
        for (int i = tid; i < nvec; i += ZERO_BLOCKS * 256) p[i] = z;
        return;
    }

    // ---- GEMM: gates[b][n] = sum_k Xcat[b][k] * Wcat[n][k] + biases ----
    // Xcat = [emb[prev[b]] | h0[b]] (K=800), Wcat = [w_ih | w_hh] rows n=g*400+j.
    const int jt   = blockIdx.x >> 2;   // 0..24
    const int bt   = blockIdx.x & 3;    // 0..3
    const int wave = threadIdx.x >> 6;
    const int lane = threadIdx.x & 63;

    const int b0   = bt * 64 + wave * 16;
    const int j    = jt * 16 + (lane & 15);   // gate column (per-gate)
    const int arow = b0 + (lane & 15);        // A row (batch)
    const int koff = (lane >> 4) * 8;         // k sub-offset within K=32 step

    // Pre-offset base pointers (koff folded in). 8-elem chunks never straddle
    // the 400-boundary since 400 % 8 == 0.
    const float* aemb = emb + (size_t)prev[arow] * HH + koff;
    const float* ah0  = h0  + (size_t)arow * HH + koff;
    const float* wlo  = wih + (size_t)j * HH + koff;   // + g*HSQ per gate
    const float* whi  = whh + (size_t)j * HH + koff;

    f32x4 ai = {0.f, 0.f, 0.f, 0.f};
    f32x4 af = {0.f, 0.f, 0.f, 0.f};
    f32x4 ag = {0.f, 0.f, 0.f, 0.f};
    f32x4 ao = {0.f, 0.f, 0.f, 0.f};

#pragma unroll 5
    for (int ks = 0; ks < 25; ++ks) {
        const int k0 = ks * 32;
        const bool lo = (k0 + koff) < HH;
        const int kk = lo ? k0 : k0 - HH;   // added to pre-koff'd base

        short8 a  = cvt8((lo ? aemb : ah0) + kk);
        const float* wb = (lo ? wlo : whi) + kk;
        short8 v0 = cvt8(wb + 0 * HSQ);
        short8 v1 = cvt8(wb + 1 * HSQ);
        short8 v2 = cvt8(wb + 2 * HSQ);
        short8 v3 = cvt8(wb + 3 * HSQ);

        ai = __builtin_amdgcn_mfma_f32_16x16x32_bf16(a, v0, ai, 0, 0, 0);
        af = __builtin_amdgcn_mfma_f32_16x16x32_bf16(a, v1, af, 0, 0, 0);
        ag = __builtin_amdgcn_mfma_f32_16x16x32_bf16(a, v2, ag, 0, 0, 0);
        ao = __builtin_amdgcn_mfma_f32_16x16x32_bf16(a, v3, ao, 0, 0, 0);
    }

    const float bi = bih[0 * HH + j] + bhh[0 * HH + j];
    const float bf = bih[1 * HH + j] + bhh[1 * HH + j];
    const float bg = bih[2 * HH + j] + bhh[2 * HH + j];
    const float bo = bih[3 * HH + j] + bhh[3 * HH + j];

#pragma unroll
    for (int r = 0; r < 4; ++r) {
        const int b = b0 + (lane >> 4) * 4 + r;   // C/D row mapping (m89-verified)
        float vi = ai[r] + bi;
        float vf = af[r] + bf;
        float vg = ag[r] + bg;
        float vo = ao[r] + bo;
        float ig = sigmoidf_(vi);
        float fg = sigmoidf_(vf);
        float gg = tanh_stable(vg);
        float og = sigmoidf_(vo);
        float cp = c0[(size_t)b * HH + j];
        float c  = fg * cp + ig * gg;
        float h  = og * tanh_stable(c);
        out[PRED_N + (size_t)b * HH + j]        = h;
        out[PRED_N + BH_N + (size_t)b * HH + j] = c;
    }
}

extern "C" void kernel_launch(void* const* d_in, const int* in_sizes, int n_in,
                              void* d_out, int out_size, void* d_ws, size_t ws_size,
                              hipStream_t stream) {
    const int*   prev = (const int*)d_in[0];
    const float* h0   = (const float*)d_in[1];
    const float* c0   = (const float*)d_in[2];
    // d_in[3] encoder_outputs: dead (softmax over size-1 axis -> t unused by live path? t feeds
    // h_att, but h_att only feeds y -> log_softmax(axis=1, size 1) -> pred == 0. All dead.)
    const float* emb  = (const float*)d_in[4];
    const float* wih  = (const float*)d_in[5];
    const float* whh  = (const float*)d_in[6];
    const float* bih  = (const float*)d_in[7];
    const float* bhh  = (const float*)d_in[8];
    // d_in[9..14]: W1/W2/W_w/W_b dead for the same reason.

    float* out = (float*)d_out;

    decoder_fused_kernel<<<TOTAL_BLOCKS, 256, 0, stream>>>(
        prev, h0, c0, emb, wih, whh, bih, bhh, out);
}

// Round 3
// 23.337 us; speedup vs baseline: 1.6479x; 1.6479x over previous
//
#include <hip/hip_runtime.h>
#include <hip/hip_bf16.h>

// Decoder step, MI355X. Live math only:
//   pred = 0 exactly (log_softmax over size-1 axis)
//   h,c  = single LSTM cell step
// Two dispatches:
//   1) prep: zero pred (32.77MB) + pack [x|h] and [w_ih|w_hh] to bf16 (coalesced)
//   2) lstm: bf16 MFMA GEMM (M=256,N=1600,K=800) + in-register gate epilogue

#define HH 400          // hidden
#define BB 256          // batch
#define KK 800          // concat K = [x | h_prev]
#define NG 1600         // 4*H gate rows
#define PRED_N 8192000  // 256*32000
#define BH_N   102400   // 256*400

#define PREP_BLOCKS 2048
#define PREP_THREADS (PREP_BLOCKS * 256)       // 524288
#define W_CHUNKS (NG * KK / 8)                  // 160000 short8 chunks
#define X_CHUNKS (BB * KK / 8)                  // 25600
#define PRED_VEC (PRED_N / 4)                   // 2048000 f32x4 stores

typedef __attribute__((ext_vector_type(8))) short short8;
typedef __attribute__((ext_vector_type(4))) float f32x4;

__device__ __forceinline__ float sigmoidf_(float x) {
    return 1.0f / (1.0f + __expf(-x));
}
__device__ __forceinline__ float tanh_stable(float x) {
    float ax = fabsf(x);
    float e  = __expf(-2.0f * ax);
    float r  = (1.0f - e) / (1.0f + e);
    return copysignf(r, x);
}

// 8 contiguous fp32 (32B-aligned) -> bf16x8
__device__ __forceinline__ short8 cvt8(const float* __restrict__ s) {
    f32x4 v0 = *reinterpret_cast<const f32x4*>(s);
    f32x4 v1 = *reinterpret_cast<const f32x4*>(s + 4);
    union { short8 sv; __hip_bfloat16 h[8]; } u;
#pragma unroll
    for (int i = 0; i < 4; ++i) {
        u.h[i]     = __float2bfloat16(v0[i]);
        u.h[i + 4] = __float2bfloat16(v1[i]);
    }
    return u.sv;
}

// One pass: pack weights + pack x + zero pred. All accesses flat-contiguous.
__launch_bounds__(256)
__global__ void prep_kernel(const int* __restrict__ prev,
                            const float* __restrict__ h0,
                            const float* __restrict__ emb,
                            const float* __restrict__ wih,
                            const float* __restrict__ whh,
                            __hip_bfloat16* __restrict__ xcat,
                            __hip_bfloat16* __restrict__ wcat,
                            float* __restrict__ out) {
    const int tid = blockIdx.x * 256 + threadIdx.x;

    if (tid < W_CHUNKS) {
        // Wcat[n][k] = k<400 ? wih[n][k] : whh[n][k-400]; 8-chunks don't straddle (400%8==0)
        const int e0 = tid * 8;
        const int n  = e0 / KK;
        const int k  = e0 % KK;
        const float* src = (k < HH) ? (wih + (size_t)n * HH + k)
                                    : (whh + (size_t)n * HH + (k - HH));
        reinterpret_cast<short8*>(wcat)[tid] = cvt8(src);
    } else if (tid < W_CHUNKS + X_CHUNKS) {
        const int t  = tid - W_CHUNKS;
        const int e0 = t * 8;
        const int b  = e0 / KK;
        const int k  = e0 % KK;
        const float* src = (k < HH) ? (emb + (size_t)prev[b] * HH + k)
                                    : (h0 + (size_t)b * HH + (k - HH));
        reinterpret_cast<short8*>(xcat)[t] = cvt8(src);
    }

    // zero pred region (exactly 0: log_softmax over size-1 axis)
    f32x4 z = {0.f, 0.f, 0.f, 0.f};
    f32x4* p = reinterpret_cast<f32x4*>(out);
    for (int i = tid; i < PRED_VEC; i += PREP_THREADS) p[i] = z;
}

// GEMM (gates = Xcat @ Wcat^T + biases) + LSTM epilogue. grid=(25,4), block=256.
// Each wave: 16(b) x 16(j) tile, 4 accumulators (gates at j, j+400, j+800, j+1200).
__launch_bounds__(256, 2)
__global__ void lstm_kernel(const __hip_bfloat16* __restrict__ xcat,
                            const __hip_bfloat16* __restrict__ wcat,
                            const float* __restrict__ bih,
                            const float* __restrict__ bhh,
                            const float* __restrict__ c0,
                            float* __restrict__ out) {
    const int jt   = blockIdx.x;          // 0..24
    const int bt   = blockIdx.y;          // 0..3
    const int wave = threadIdx.x >> 6;
    const int lane = threadIdx.x & 63;

    const int b0   = bt * 64 + wave * 16;
    const int j    = jt * 16 + (lane & 15);   // gate column
    const int arow = b0 + (lane & 15);        // A row (batch)
    const int koff = (lane >> 4) * 8;         // k sub-offset within K=32 step

    const short8* ap  = reinterpret_cast<const short8*>(xcat + (size_t)arow * KK + koff);
    const short8* bp0 = reinterpret_cast<const short8*>(wcat + (size_t)(0 * HH + j) * KK + koff);
    const short8* bp1 = reinterpret_cast<const short8*>(wcat + (size_t)(1 * HH + j) * KK + koff);
    const short8* bp2 = reinterpret_cast<const short8*>(wcat + (size_t)(2 * HH + j) * KK + koff);
    const short8* bp3 = reinterpret_cast<const short8*>(wcat + (size_t)(3 * HH + j) * KK + koff);

    f32x4 ai = {0.f, 0.f, 0.f, 0.f};
    f32x4 af = {0.f, 0.f, 0.f, 0.f};
    f32x4 ag = {0.f, 0.f, 0.f, 0.f};
    f32x4 ao = {0.f, 0.f, 0.f, 0.f};

#pragma unroll
    for (int ks = 0; ks < KK / 32; ++ks) {
        short8 a = ap[ks * 4];   // +32 bf16 per step
        ai = __builtin_amdgcn_mfma_f32_16x16x32_bf16(a, bp0[ks * 4], ai, 0, 0, 0);
        af = __builtin_amdgcn_mfma_f32_16x16x32_bf16(a, bp1[ks * 4], af, 0, 0, 0);
        ag = __builtin_amdgcn_mfma_f32_16x16x32_bf16(a, bp2[ks * 4], ag, 0, 0, 0);
        ao = __builtin_amdgcn_mfma_f32_16x16x32_bf16(a, bp3[ks * 4], ao, 0, 0, 0);
    }

    const float bi = bih[0 * HH + j] + bhh[0 * HH + j];
    const float bf = bih[1 * HH + j] + bhh[1 * HH + j];
    const float bg = bih[2 * HH + j] + bhh[2 * HH + j];
    const float bo = bih[3 * HH + j] + bhh[3 * HH + j];

#pragma unroll
    for (int r = 0; r < 4; ++r) {
        const int b = b0 + (lane >> 4) * 4 + r;   // C/D row mapping (m89-verified)
        float vi = ai[r] + bi;
        float vf = af[r] + bf;
        float vg = ag[r] + bg;
        float vo = ao[r] + bo;
        float ig = sigmoidf_(vi);
        float fg = sigmoidf_(vf);
        float gg = tanh_stable(vg);
        float og = sigmoidf_(vo);
        float cp = c0[(size_t)b * HH + j];
        float c  = fg * cp + ig * gg;
        float h  = og * tanh_stable(c);
        out[PRED_N + (size_t)b * HH + j]        = h;
        out[PRED_N + BH_N + (size_t)b * HH + j] = c;
    }
}

extern "C" void kernel_launch(void* const* d_in, const int* in_sizes, int n_in,
                              void* d_out, int out_size, void* d_ws, size_t ws_size,
                              hipStream_t stream) {
    const int*   prev = (const int*)d_in[0];
    const float* h0   = (const float*)d_in[1];
    const float* c0   = (const float*)d_in[2];
    // d_in[3] encoder_outputs: dead (feeds only pred, which log_softmax(axis=1,size1) zeroes)
    const float* emb  = (const float*)d_in[4];
    const float* wih  = (const float*)d_in[5];
    const float* whh  = (const float*)d_in[6];
    const float* bih  = (const float*)d_in[7];
    const float* bhh  = (const float*)d_in[8];
    // d_in[9..14]: W1/W2/W_w/W_b dead for the same reason.

    float* out = (float*)d_out;

    __hip_bfloat16* xcat = (__hip_bfloat16*)d_ws;                    // 256*800 bf16
    __hip_bfloat16* wcat = (__hip_bfloat16*)((char*)d_ws + 409600);  // 1600*800 bf16

    prep_kernel<<<PREP_BLOCKS, 256, 0, stream>>>(prev, h0, emb, wih, whh, xcat, wcat, out);

    dim3 grid(25, 4);
    lstm_kernel<<<grid, 256, 0, stream>>>(xcat, wcat, bih, bhh, c0, out);
}

// Round 4
// 21.786 us; speedup vs baseline: 1.7652x; 1.0712x over previous
//
#include <hip/hip_runtime.h>
#include <hip/hip_bf16.h>

// Decoder step, MI355X. Live math only:
//   pred = 0 exactly (log_softmax over size-1 axis)
//   h,c  = single LSTM cell step
// Two dispatches, rebalanced so the 32.8MB pred-zero overlaps the GEMM:
//   k1: pack [x|h] and [w_ih|w_hh] to bf16 (coalesced)   ~24.7MB traffic
//   k2: blocks 0..99 = MFMA GEMM + LSTM epilogue; blocks 100.. = zero pred

#define HH 400          // hidden
#define BB 256          // batch
#define KK 800          // concat K = [x | h_prev]
#define NG 1600         // 4*H gate rows
#define PRED_N 8192000  // 256*32000
#define BH_N   102400   // 256*400

#define W_CHUNKS (NG * KK / 8)                  // 160000 short8 chunks
#define X_CHUNKS (BB * KK / 8)                  // 25600
#define PACK_THREADS (W_CHUNKS + X_CHUNKS)      // 185600
#define PACK_BLOCKS ((PACK_THREADS + 255) / 256)

#define GEMM_BLOCKS 100
#define K2_BLOCKS 2048
#define ZERO_BLOCKS (K2_BLOCKS - GEMM_BLOCKS)
#define ZERO_THREADS (ZERO_BLOCKS * 256)
#define PRED_VEC (PRED_N / 4)                   // 2048000 f32x4 stores

typedef __attribute__((ext_vector_type(8))) short short8;
typedef __attribute__((ext_vector_type(4))) float f32x4;

__device__ __forceinline__ float sigmoidf_(float x) {
    return 1.0f / (1.0f + __expf(-x));
}
__device__ __forceinline__ float tanh_stable(float x) {
    float ax = fabsf(x);
    float e  = __expf(-2.0f * ax);
    float r  = (1.0f - e) / (1.0f + e);
    return copysignf(r, x);
}

// 8 contiguous fp32 (32B-aligned) -> bf16x8
__device__ __forceinline__ short8 cvt8(const float* __restrict__ s) {
    f32x4 v0 = *reinterpret_cast<const f32x4*>(s);
    f32x4 v1 = *reinterpret_cast<const f32x4*>(s + 4);
    union { short8 sv; __hip_bfloat16 h[8]; } u;
#pragma unroll
    for (int i = 0; i < 4; ++i) {
        u.h[i]     = __float2bfloat16(v0[i]);
        u.h[i + 4] = __float2bfloat16(v1[i]);
    }
    return u.sv;
}

// k1: pack weights + x to bf16. All accesses flat-contiguous/coalesced.
__launch_bounds__(256)
__global__ void pack_kernel(const int* __restrict__ prev,
                            const float* __restrict__ h0,
                            const float* __restrict__ emb,
                            const float* __restrict__ wih,
                            const float* __restrict__ whh,
                            __hip_bfloat16* __restrict__ xcat,
                            __hip_bfloat16* __restrict__ wcat) {
    const int tid = blockIdx.x * 256 + threadIdx.x;

    if (tid < W_CHUNKS) {
        // Wcat[n][k] = k<400 ? wih[n][k] : whh[n][k-400]; chunks don't straddle (400%8==0)
        const int e0 = tid * 8;
        const int n  = e0 / KK;
        const int k  = e0 % KK;
        const float* src = (k < HH) ? (wih + (size_t)n * HH + k)
                                    : (whh + (size_t)n * HH + (k - HH));
        reinterpret_cast<short8*>(wcat)[tid] = cvt8(src);
    } else if (tid < PACK_THREADS) {
        const int t  = tid - W_CHUNKS;
        const int e0 = t * 8;
        const int b  = e0 / KK;
        const int k  = e0 % KK;
        const float* src = (k < HH) ? (emb + (size_t)prev[b] * HH + k)
                                    : (h0 + (size_t)b * HH + (k - HH));
        reinterpret_cast<short8*>(xcat)[t] = cvt8(src);
    }
}

// k2: blocks 0..99 GEMM (gates = Xcat @ Wcat^T + biases) + LSTM epilogue;
//     blocks 100.. grid-stride zero of the 32.77MB pred region (overlaps GEMM).
__launch_bounds__(256)
__global__ void lstm_zero_kernel(const __hip_bfloat16* __restrict__ xcat,
                                 const __hip_bfloat16* __restrict__ wcat,
                                 const float* __restrict__ bih,
                                 const float* __restrict__ bhh,
                                 const float* __restrict__ c0,
                                 float* __restrict__ out) {
    if (blockIdx.x >= GEMM_BLOCKS) {
        const int tid = (blockIdx.x - GEMM_BLOCKS) * 256 + threadIdx.x;
        f32x4 z = {0.f, 0.f, 0.f, 0.f};
        f32x4* p = reinterpret_cast<f32x4*>(out);
        for (int i = tid; i < PRED_VEC; i += ZERO_THREADS) p[i] = z;
        return;
    }

    const int jt   = blockIdx.x >> 2;     // 0..24
    const int bt   = blockIdx.x & 3;      // 0..3
    const int wave = threadIdx.x >> 6;
    const int lane = threadIdx.x & 63;

    const int b0   = bt * 64 + wave * 16;
    const int j    = jt * 16 + (lane & 15);   // gate column
    const int arow = b0 + (lane & 15);        // A row (batch)
    const int koff = (lane >> 4) * 8;         // k sub-offset within K=32 step

    const short8* ap  = reinterpret_cast<const short8*>(xcat + (size_t)arow * KK + koff);
    const short8* bp0 = reinterpret_cast<const short8*>(wcat + (size_t)(0 * HH + j) * KK + koff);
    const short8* bp1 = reinterpret_cast<const short8*>(wcat + (size_t)(1 * HH + j) * KK + koff);
    const short8* bp2 = reinterpret_cast<const short8*>(wcat + (size_t)(2 * HH + j) * KK + koff);
    const short8* bp3 = reinterpret_cast<const short8*>(wcat + (size_t)(3 * HH + j) * KK + koff);

    f32x4 ai = {0.f, 0.f, 0.f, 0.f};
    f32x4 af = {0.f, 0.f, 0.f, 0.f};
    f32x4 ag = {0.f, 0.f, 0.f, 0.f};
    f32x4 ao = {0.f, 0.f, 0.f, 0.f};

#pragma unroll
    for (int ks = 0; ks < KK / 32; ++ks) {
        short8 a = ap[ks * 4];   // +32 bf16 per step
        ai = __builtin_amdgcn_mfma_f32_16x16x32_bf16(a, bp0[ks * 4], ai, 0, 0, 0);
        af = __builtin_amdgcn_mfma_f32_16x16x32_bf16(a, bp1[ks * 4], af, 0, 0, 0);
        ag = __builtin_amdgcn_mfma_f32_16x16x32_bf16(a, bp2[ks * 4], ag, 0, 0, 0);
        ao = __builtin_amdgcn_mfma_f32_16x16x32_bf16(a, bp3[ks * 4], ao, 0, 0, 0);
    }

    const float bi = bih[0 * HH + j] + bhh[0 * HH + j];
    const float bf = bih[1 * HH + j] + bhh[1 * HH + j];
    const float bg = bih[2 * HH + j] + bhh[2 * HH + j];
    const float bo = bih[3 * HH + j] + bhh[3 * HH + j];

#pragma unroll
    for (int r = 0; r < 4; ++r) {
        const int b = b0 + (lane >> 4) * 4 + r;   // C/D row mapping (m89-verified)
        float vi = ai[r] + bi;
        float vf = af[r] + bf;
        float vg = ag[r] + bg;
        float vo = ao[r] + bo;
        float ig = sigmoidf_(vi);
        float fg = sigmoidf_(vf);
        float gg = tanh_stable(vg);
        float og = sigmoidf_(vo);
        float cp = c0[(size_t)b * HH + j];
        float c  = fg * cp + ig * gg;
        float h  = og * tanh_stable(c);
        out[PRED_N + (size_t)b * HH + j]        = h;
        out[PRED_N + BH_N + (size_t)b * HH + j] = c;
    }
}

extern "C" void kernel_launch(void* const* d_in, const int* in_sizes, int n_in,
                              void* d_out, int out_size, void* d_ws, size_t ws_size,
                              hipStream_t stream) {
    const int*   prev = (const int*)d_in[0];
    const float* h0   = (const float*)d_in[1];
    const float* c0   = (const float*)d_in[2];
    // d_in[3] encoder_outputs: dead (feeds only pred, which log_softmax(axis=1,size1) zeroes)
    const float* emb  = (const float*)d_in[4];
    const float* wih  = (const float*)d_in[5];
    const float* whh  = (const float*)d_in[6];
    const float* bih  = (const float*)d_in[7];
    const float* bhh  = (const float*)d_in[8];
    // d_in[9..14]: W1/W2/W_w/W_b dead for the same reason.

    float* out = (float*)d_out;

    __hip_bfloat16* xcat = (__hip_bfloat16*)d_ws;                    // 256*800 bf16
    __hip_bfloat16* wcat = (__hip_bfloat16*)((char*)d_ws + 409600);  // 1600*800 bf16

    pack_kernel<<<PACK_BLOCKS, 256, 0, stream>>>(prev, h0, emb, wih, whh, xcat, wcat);

    lstm_zero_kernel<<<K2_BLOCKS, 256, 0, stream>>>(xcat, wcat, bih, bhh, c0, out);
}